// Round 1
// baseline (698.127 us; speedup 1.0000x reference)
//
#include <hip/hip_runtime.h>
#include <hip/hip_bf16.h>

typedef __bf16 bf16;
typedef __bf16 bf16x8 __attribute__((ext_vector_type(8)));
typedef __bf16 bf16x4 __attribute__((ext_vector_type(4)));
typedef float  f32x4  __attribute__((ext_vector_type(4)));

#define N_HEADS 16
#define D_HEAD  64
#define SEQ     1024
#define BATCH   8
#define MROWS   (BATCH * SEQ)   // 8192

// ---- async global->LDS 16B (per-lane lds ptr = wave base + lane*16) ----
__device__ __forceinline__ void gld_lds16(const void* g, void* l) {
    __builtin_amdgcn_global_load_lds(
        (const __attribute__((address_space(1))) void*)g,
        (__attribute__((address_space(3))) void*)l, 16, 0, 0);
}

// =======================================================================
// Weight convert + transpose: W f32 [K][N] -> Wt bf16 [N][K]
// =======================================================================
__global__ __launch_bounds__(256)
void wconv_t(const float* __restrict__ W, bf16* __restrict__ Wt, int K, int N)
{
    __shared__ float tile[32][33];
    const int tx = threadIdx.x & 31, ty = threadIdx.x >> 5;   // 32 x 8
    const int nb = blockIdx.x * 32, kb = blockIdx.y * 32;
    #pragma unroll
    for (int i = 0; i < 4; ++i)
        tile[ty + i * 8][tx] = W[(size_t)(kb + ty + i * 8) * N + nb + tx];
    __syncthreads();
    #pragma unroll
    for (int i = 0; i < 4; ++i)
        Wt[(size_t)(nb + ty + i * 8) * K + kb + tx] = (bf16)tile[tx][ty + i * 8];
}

// =======================================================================
// LayerNorm over last dim (1024). One block per row. Writes bf16 + f32.
// =======================================================================
__global__ __launch_bounds__(256)
void ln_kernel(const float* __restrict__ x, const float* __restrict__ g,
               const float* __restrict__ b, bf16* __restrict__ obf,
               float* __restrict__ of)
{
    const int row = blockIdx.x;
    const int tid = threadIdx.x;
    const float4 v = ((const float4*)(x + (size_t)row * 1024))[tid];
    float s  = v.x + v.y + v.z + v.w;
    float sq = v.x * v.x + v.y * v.y + v.z * v.z + v.w * v.w;
    #pragma unroll
    for (int off = 32; off; off >>= 1) {
        s  += __shfl_down(s, off);
        sq += __shfl_down(sq, off);
    }
    __shared__ float red[8];
    const int wid = tid >> 6, lid = tid & 63;
    if (lid == 0) { red[wid] = s; red[4 + wid] = sq; }
    __syncthreads();
    if (tid == 0) {
        float ts = red[0] + red[1] + red[2] + red[3];
        float tq = red[4] + red[5] + red[6] + red[7];
        float mean = ts * (1.f / 1024.f);
        float var  = tq * (1.f / 1024.f) - mean * mean;
        red[0] = mean;
        red[1] = rsqrtf(var + 1e-6f);
    }
    __syncthreads();
    const float mean = red[0], rstd = red[1];
    const float4 gg = ((const float4*)g)[tid];
    const float4 bb = ((const float4*)b)[tid];
    float y0 = (v.x - mean) * rstd * gg.x + bb.x;
    float y1 = (v.y - mean) * rstd * gg.y + bb.y;
    float y2 = (v.z - mean) * rstd * gg.z + bb.z;
    float y3 = (v.w - mean) * rstd * gg.w + bb.w;
    float4 o; o.x = y0; o.y = y1; o.z = y2; o.w = y3;
    ((float4*)(of + (size_t)row * 1024))[tid] = o;
    bf16x4 ob; ob[0] = (bf16)y0; ob[1] = (bf16)y1; ob[2] = (bf16)y2; ob[3] = (bf16)y3;
    ((bf16x4*)(obf + (size_t)row * 1024))[tid] = ob;
}

// =======================================================================
// GEMM: C[M,N] = A[M,K] @ Bt[N,K]^T (+bias, epilogue variants)
// 128x128 tile, BK=32, 4 waves of 64x64, mfma 16x16x32 bf16 (m97 structure)
// EPI 0: out bf16 permuted [b,h,s,d] (QKV)
// EPI 1: out f32 = acc + bias + resid
// EPI 2: out bf16 = relu(acc + bias)
// =======================================================================
template <int EPI>
__global__ __launch_bounds__(256)
void gemm_bt(const bf16* __restrict__ A, const bf16* __restrict__ Bt,
             const float* __restrict__ bias, const float* __restrict__ resid,
             void* __restrict__ Cout, int M, int N, int K)
{
    __shared__ __attribute__((aligned(16))) bf16 a_lds[128 * 32];
    __shared__ __attribute__((aligned(16))) bf16 b_lds[128 * 32];
    const int tid = threadIdx.x;
    const int l = tid & 63, w = tid >> 6;
    const int lo = l & 15, hi = l >> 4;
    const int m0 = blockIdx.y * 128, n0 = blockIdx.x * 128;
    const int wrow = (w >> 1) * 64, wcol = (w & 1) * 64;
    const int srow = tid >> 2;            // 0..63
    const int scol = (tid & 3) * 8;       // 0,8,16,24

    f32x4 acc[4][4];
    #pragma unroll
    for (int i = 0; i < 4; ++i)
        #pragma unroll
        for (int j = 0; j < 4; ++j) acc[i][j] = f32x4{0.f, 0.f, 0.f, 0.f};

    const int nkt = K >> 5;
    for (int kt = 0; kt < nkt; ++kt) {
        __syncthreads();   // previous iter's reads done before overwrite
        const bf16* ag = A  + (size_t)(m0 + srow) * K + kt * 32 + scol;
        const bf16* bg = Bt + (size_t)(n0 + srow) * K + kt * 32 + scol;
        gld_lds16(ag,                  &a_lds[srow * 32 + scol]);
        gld_lds16(ag + (size_t)64 * K, &a_lds[(64 + srow) * 32 + scol]);
        gld_lds16(bg,                  &b_lds[srow * 32 + scol]);
        gld_lds16(bg + (size_t)64 * K, &b_lds[(64 + srow) * 32 + scol]);
        asm volatile("s_waitcnt vmcnt(0)" ::: "memory");
        __syncthreads();

        bf16x8 af[4], bfr[4];
        #pragma unroll
        for (int m = 0; m < 4; ++m)
            af[m] = *(const bf16x8*)&a_lds[(wrow + m * 16 + lo) * 32 + hi * 8];
        #pragma unroll
        for (int n = 0; n < 4; ++n)
            bfr[n] = *(const bf16x8*)&b_lds[(wcol + n * 16 + lo) * 32 + hi * 8];
        #pragma unroll
        for (int m = 0; m < 4; ++m)
            #pragma unroll
            for (int n = 0; n < 4; ++n)
                acc[m][n] = __builtin_amdgcn_mfma_f32_16x16x32_bf16(af[m], bfr[n], acc[m][n], 0, 0, 0);
    }

    // epilogue: C row = m0+wrow+m*16+hi*4+r, col = n0+wcol+n*16+lo
    #pragma unroll
    for (int m = 0; m < 4; ++m) {
        const int Rbase = m0 + wrow + m * 16 + hi * 4;
        #pragma unroll
        for (int n = 0; n < 4; ++n) {
            const int Cc = n0 + wcol + n * 16 + lo;
            const float bv = bias[Cc];
            #pragma unroll
            for (int r = 0; r < 4; ++r) {
                const int Rr = Rbase + r;
                float vv = acc[m][n][r] + bv;
                if (EPI == 0) {
                    const int b_ = Rr >> 10, s_ = Rr & 1023;
                    const int h_ = Cc >> 6,  d_ = Cc & 63;
                    ((bf16*)Cout)[(((size_t)(b_ * 16 + h_) * 1024 + s_) << 6) + d_] = (bf16)vv;
                } else if (EPI == 1) {
                    vv += resid[(size_t)Rr * N + Cc];
                    ((float*)Cout)[(size_t)Rr * N + Cc] = vv;
                } else {
                    vv = fmaxf(vv, 0.f);
                    ((bf16*)Cout)[(size_t)Rr * N + Cc] = (bf16)vv;
                }
            }
        }
    }
}

// =======================================================================
// Flash attention. Block = (qt, h, b); 256 thr = 4 waves x 16 q-rows.
// q,k,v: bf16 [b,h,s,d]. ctx out: bf16 [b,s,h,d] (GEMM-ready [M,1024]).
// =======================================================================
__global__ __launch_bounds__(256)
void attn_kernel(const bf16* __restrict__ q, const bf16* __restrict__ k,
                 const bf16* __restrict__ v, const unsigned char* __restrict__ mask,
                 bf16* __restrict__ ctx)
{
    __shared__ __attribute__((aligned(16))) bf16 q_lds[64][72];
    __shared__ __attribute__((aligned(16))) bf16 k_lds[64][72];
    __shared__ __attribute__((aligned(16))) bf16 vt_lds[64][72];   // [d][kv]
    __shared__ __attribute__((aligned(16))) bf16 p_lds[4][16][72];
    __shared__ __attribute__((aligned(16))) unsigned char m_lds[64][64];

    const int qt = blockIdx.x, hh = blockIdx.y, bb = blockIdx.z;
    const int bh = bb * N_HEADS + hh;
    const int tid = threadIdx.x;
    const int w = tid >> 6, l = tid & 63;
    const int lo = l & 15, hi = l >> 4;

    {   // stage Q tile [64][64]
        const bf16* qg = q + ((size_t)bh * SEQ + qt * 64) * D_HEAD;
        #pragma unroll
        for (int i = 0; i < 2; ++i) {
            const int e = (i * 256 + tid) * 8;
            const int r = e >> 6, c = e & 63;
            *(uint4*)&q_lds[r][c] = *(const uint4*)(qg + r * 64 + c);
        }
    }

    f32x4 oacc[4];
    float m_r[4], l_r[4];
    #pragma unroll
    for (int i = 0; i < 4; ++i) {
        oacc[i] = f32x4{0.f, 0.f, 0.f, 0.f};
        m_r[i] = -__builtin_inff();
        l_r[i] = 0.f;
    }

    for (int kt = 0; kt < 16; ++kt) {
        __syncthreads();
        const bf16* kg = k + ((size_t)bh * SEQ + kt * 64) * D_HEAD;
        const bf16* vg = v + ((size_t)bh * SEQ + kt * 64) * D_HEAD;
        #pragma unroll
        for (int i = 0; i < 2; ++i) {
            const int e = (i * 256 + tid) * 8;
            const int r = e >> 6, c = e & 63;
            *(uint4*)&k_lds[r][c] = *(const uint4*)(kg + r * 64 + c);
            uint4 tv = *(const uint4*)(vg + r * 64 + c);
            const bf16* pv = (const bf16*)&tv;
            #pragma unroll
            for (int j = 0; j < 8; ++j) vt_lds[c + j][r] = pv[j];
        }
        {   // mask tile [64 q][64 k] bytes
            const int r = tid >> 2, c0 = (tid & 3) * 16;
            *(uint4*)&m_lds[r][c0] =
                *(const uint4*)(mask + ((size_t)bb * SEQ + qt * 64 + r) * SEQ + kt * 64 + c0);
        }
        __syncthreads();

        // S = Q K^T for this wave's 16 rows x 64 cols
        f32x4 sf[4];
        #pragma unroll
        for (int ct = 0; ct < 4; ++ct) {
            f32x4 sa = f32x4{0.f, 0.f, 0.f, 0.f};
            #pragma unroll
            for (int kk = 0; kk < 2; ++kk) {
                bf16x8 a   = *(const bf16x8*)&q_lds[w * 16 + lo][kk * 32 + hi * 8];
                bf16x8 bfr = *(const bf16x8*)&k_lds[ct * 16 + lo][kk * 32 + hi * 8];
                sa = __builtin_amdgcn_mfma_f32_16x16x32_bf16(a, bfr, sa, 0, 0, 0);
            }
            sf[ct] = sa;
        }

        // scale + mask + online softmax (row = w*16 + hi*4 + r, col = ct*16 + lo)
        float pm[4];
        #pragma unroll
        for (int r = 0; r < 4; ++r) {
            #pragma unroll
            for (int ct = 0; ct < 4; ++ct) {
                float sv = sf[ct][r] * 0.125f;
                if (m_lds[w * 16 + hi * 4 + r][ct * 16 + lo]) sv = -__builtin_inff();
                sf[ct][r] = sv;
            }
            float t0 = fmaxf(fmaxf(sf[0][r], sf[1][r]), fmaxf(sf[2][r], sf[3][r]));
            #pragma unroll
            for (int off = 1; off < 16; off <<= 1) t0 = fmaxf(t0, __shfl_xor(t0, off));
            pm[r] = t0;
        }
        float scl[4];
        #pragma unroll
        for (int r = 0; r < 4; ++r) {
            const float mn = fmaxf(m_r[r], pm[r]);
            scl[r] = __expf(m_r[r] - mn);
            m_r[r] = mn;
            float acc_s = 0.f;
            #pragma unroll
            for (int ct = 0; ct < 4; ++ct) {
                const float p = __expf(sf[ct][r] - mn);
                sf[ct][r] = p;
                acc_s += p;
            }
            #pragma unroll
            for (int off = 1; off < 16; off <<= 1) acc_s += __shfl_xor(acc_s, off);
            l_r[r] = l_r[r] * scl[r] + acc_s;
        }
        #pragma unroll
        for (int n = 0; n < 4; ++n)
            #pragma unroll
            for (int r = 0; r < 4; ++r) oacc[n][r] *= scl[r];

        // P -> LDS (per-wave private)
        #pragma unroll
        for (int ct = 0; ct < 4; ++ct)
            #pragma unroll
            for (int r = 0; r < 4; ++r)
                p_lds[w][hi * 4 + r][ct * 16 + lo] = (bf16)sf[ct][r];
        asm volatile("s_waitcnt lgkmcnt(0)" ::: "memory");

        // O += P @ V
        #pragma unroll
        for (int n = 0; n < 4; ++n)
            #pragma unroll
            for (int kk = 0; kk < 2; ++kk) {
                bf16x8 a   = *(const bf16x8*)&p_lds[w][lo][kk * 32 + hi * 8];
                bf16x8 bfr = *(const bf16x8*)&vt_lds[n * 16 + lo][kk * 32 + hi * 8];
                oacc[n] = __builtin_amdgcn_mfma_f32_16x16x32_bf16(a, bfr, oacc[n], 0, 0, 0);
            }
    }

    // epilogue: ctx[b, s, h, d] = O / l
    #pragma unroll
    for (int r = 0; r < 4; ++r) {
        const float inv = 1.f / l_r[r];
        const size_t srow = (size_t)bb * SEQ + qt * 64 + w * 16 + hi * 4 + r;
        const size_t base = (srow * N_HEADS + hh) * D_HEAD;
        #pragma unroll
        for (int n = 0; n < 4; ++n)
            ctx[base + n * 16 + lo] = (bf16)(oacc[n][r] * inv);
    }
}

// =======================================================================
extern "C" void kernel_launch(void* const* d_in, const int* in_sizes, int n_in,
                              void* d_out, int out_size, void* d_ws, size_t ws_size,
                              hipStream_t stream)
{
    const float* x      = (const float*)d_in[0];
    const unsigned char* mask = (const unsigned char*)d_in[1];
    const float* gamma1 = (const float*)d_in[2];
    const float* beta1  = (const float*)d_in[3];
    const float* Wq     = (const float*)d_in[4];
    const float* bq     = (const float*)d_in[5];
    const float* Wk     = (const float*)d_in[6];
    const float* bk     = (const float*)d_in[7];
    const float* Wv     = (const float*)d_in[8];
    const float* bv     = (const float*)d_in[9];
    const float* Wo     = (const float*)d_in[10];
    const float* bo     = (const float*)d_in[11];
    const float* gamma2 = (const float*)d_in[12];
    const float* beta2  = (const float*)d_in[13];
    const float* W1     = (const float*)d_in[14];
    const float* b1     = (const float*)d_in[15];
    const float* W2     = (const float*)d_in[16];
    const float* b2     = (const float*)d_in[17];

    char* ws = (char*)d_ws;
    const size_t MB = 1u << 20;
    bf16* wqt  = (bf16*)(ws + 0 * MB);    // [1024][1024] bf16 (2MB)
    bf16* wkt  = (bf16*)(ws + 2 * MB);
    bf16* wvt  = (bf16*)(ws + 4 * MB);
    bf16* wot  = (bf16*)(ws + 6 * MB);
    bf16* w1t  = (bf16*)(ws + 8 * MB);    // [4096][1024] (8MB)
    bf16* w2t  = (bf16*)(ws + 16 * MB);   // [1024][4096] (8MB)
    bf16* xn1b = (bf16*)(ws + 24 * MB);   // [8192][1024] (16MB)
    float* xn1f = (float*)(ws + 40 * MB); // (32MB)
    bf16* qb   = (bf16*)(ws + 72 * MB);   // [b,h,s,d] (16MB)
    bf16* kb_  = (bf16*)(ws + 88 * MB);
    bf16* vb   = (bf16*)(ws + 104 * MB);
    bf16* ctx  = (bf16*)(ws + 120 * MB);  // [b,s,h,d] (16MB)
    bf16* hbuf = (bf16*)(ws + 72 * MB);   // [8192][4096] (64MB) aliases q/k/v/ctx (dead by then)
    bf16* xn2b = (bf16*)(ws + 136 * MB);  // (16MB)
    float* xn2f = (float*)(ws + 152 * MB);// (32MB) -> total 184MB
    float* x2f = (float*)d_out;           // reuse d_out as x2 scratch

    // weights -> bf16 transposed
    wconv_t<<<dim3(32, 32),  256, 0, stream>>>(Wq, wqt, 1024, 1024);
    wconv_t<<<dim3(32, 32),  256, 0, stream>>>(Wk, wkt, 1024, 1024);
    wconv_t<<<dim3(32, 32),  256, 0, stream>>>(Wv, wvt, 1024, 1024);
    wconv_t<<<dim3(32, 32),  256, 0, stream>>>(Wo, wot, 1024, 1024);
    wconv_t<<<dim3(128, 32), 256, 0, stream>>>(W1, w1t, 1024, 4096);
    wconv_t<<<dim3(32, 128), 256, 0, stream>>>(W2, w2t, 4096, 1024);

    // xn1 = LN1(x)
    ln_kernel<<<MROWS, 256, 0, stream>>>(x, gamma1, beta1, xn1b, xn1f);

    // q,k,v projections
    gemm_bt<0><<<dim3(8, 64), 256, 0, stream>>>(xn1b, wqt, bq, nullptr, qb,  MROWS, 1024, 1024);
    gemm_bt<0><<<dim3(8, 64), 256, 0, stream>>>(xn1b, wkt, bk, nullptr, kb_, MROWS, 1024, 1024);
    gemm_bt<0><<<dim3(8, 64), 256, 0, stream>>>(xn1b, wvt, bv, nullptr, vb,  MROWS, 1024, 1024);

    // attention
    attn_kernel<<<dim3(16, 16, 8), 256, 0, stream>>>(qb, kb_, vb, mask, ctx);

    // x2 = xn1 + ctx @ Wo + bo   (into d_out as scratch)
    gemm_bt<1><<<dim3(8, 64), 256, 0, stream>>>(ctx, wot, bo, xn1f, x2f, MROWS, 1024, 1024);

    // xn2 = LN2(x2)
    ln_kernel<<<MROWS, 256, 0, stream>>>(x2f, gamma2, beta2, xn2b, xn2f);

    // h = relu(xn2 @ W1 + b1)
    gemm_bt<2><<<dim3(32, 64), 256, 0, stream>>>(xn2b, w1t, b1, nullptr, hbuf, MROWS, 4096, 1024);

    // out = xn2 + h @ W2 + b2
    gemm_bt<1><<<dim3(8, 64), 256, 0, stream>>>(hbuf, w2t, b2, xn2f, (float*)d_out, MROWS, 1024, 4096);
}

// Round 2
// 661.020 us; speedup vs baseline: 1.0561x; 1.0561x over previous
//
#include <hip/hip_runtime.h>
#include <hip/hip_bf16.h>

typedef __bf16 bf16;
typedef __bf16 bf16x8 __attribute__((ext_vector_type(8)));
typedef __bf16 bf16x4 __attribute__((ext_vector_type(4)));
typedef float  f32x4  __attribute__((ext_vector_type(4)));

#define N_HEADS 16
#define D_HEAD  64
#define SEQ     1024
#define BATCH   8
#define MROWS   (BATCH * SEQ)   // 8192

// ---- async global->LDS 16B (per-lane lds ptr = wave base + lane*16) ----
__device__ __forceinline__ void gld_lds16(const void* g, void* l) {
    __builtin_amdgcn_global_load_lds(
        (const __attribute__((address_space(1))) void*)g,
        (__attribute__((address_space(3))) void*)l, 16, 0, 0);
}

// =======================================================================
// Weight convert + transpose: W f32 [K][N] -> Wt bf16 [N][K]
// =======================================================================
__global__ __launch_bounds__(256)
void wconv_t(const float* __restrict__ W, bf16* __restrict__ Wt, int K, int N)
{
    __shared__ float tile[32][33];
    const int tx = threadIdx.x & 31, ty = threadIdx.x >> 5;   // 32 x 8
    const int nb = blockIdx.x * 32, kb = blockIdx.y * 32;
    #pragma unroll
    for (int i = 0; i < 4; ++i)
        tile[ty + i * 8][tx] = W[(size_t)(kb + ty + i * 8) * N + nb + tx];
    __syncthreads();
    #pragma unroll
    for (int i = 0; i < 4; ++i)
        Wt[(size_t)(nb + ty + i * 8) * K + kb + tx] = (bf16)tile[tx][ty + i * 8];
}

// =======================================================================
// Bias concat: bqkv[0:1024)=bq, [1024:2048)=bk, [2048:3072)=bv
// =======================================================================
__global__ __launch_bounds__(256)
void bconcat(const float* __restrict__ bq, const float* __restrict__ bk,
             const float* __restrict__ bv, float* __restrict__ o)
{
    const int i = blockIdx.x * 256 + threadIdx.x;
    if (i < 1024)       o[i] = bq[i];
    else if (i < 2048)  o[i] = bk[i - 1024];
    else if (i < 3072)  o[i] = bv[i - 2048];
}

// =======================================================================
// Mask pack: bool bytes [B,S,S] -> bit mask u64 [B,S,S/64]
// =======================================================================
__global__ __launch_bounds__(256)
void mask_pack(const unsigned char* __restrict__ m,
               unsigned long long* __restrict__ bits)
{
    const int i = blockIdx.x * 256 + threadIdx.x;
    unsigned long long b = __ballot(m[i] != 0);
    if ((threadIdx.x & 63) == 0) bits[i >> 6] = b;
}

// =======================================================================
// LayerNorm over last dim (1024). One block per row. Writes bf16 + f32.
// =======================================================================
__global__ __launch_bounds__(256)
void ln_kernel(const float* __restrict__ x, const float* __restrict__ g,
               const float* __restrict__ b, bf16* __restrict__ obf,
               float* __restrict__ of)
{
    const int row = blockIdx.x;
    const int tid = threadIdx.x;
    const float4 v = ((const float4*)(x + (size_t)row * 1024))[tid];
    float s  = v.x + v.y + v.z + v.w;
    float sq = v.x * v.x + v.y * v.y + v.z * v.z + v.w * v.w;
    #pragma unroll
    for (int off = 32; off; off >>= 1) {
        s  += __shfl_down(s, off);
        sq += __shfl_down(sq, off);
    }
    __shared__ float red[8];
    const int wid = tid >> 6, lid = tid & 63;
    if (lid == 0) { red[wid] = s; red[4 + wid] = sq; }
    __syncthreads();
    if (tid == 0) {
        float ts = red[0] + red[1] + red[2] + red[3];
        float tq = red[4] + red[5] + red[6] + red[7];
        float mean = ts * (1.f / 1024.f);
        float var  = tq * (1.f / 1024.f) - mean * mean;
        red[0] = mean;
        red[1] = rsqrtf(var + 1e-6f);
    }
    __syncthreads();
    const float mean = red[0], rstd = red[1];
    const float4 gg = ((const float4*)g)[tid];
    const float4 bb = ((const float4*)b)[tid];
    float y0 = (v.x - mean) * rstd * gg.x + bb.x;
    float y1 = (v.y - mean) * rstd * gg.y + bb.y;
    float y2 = (v.z - mean) * rstd * gg.z + bb.z;
    float y3 = (v.w - mean) * rstd * gg.w + bb.w;
    float4 o; o.x = y0; o.y = y1; o.z = y2; o.w = y3;
    ((float4*)(of + (size_t)row * 1024))[tid] = o;
    bf16x4 ob; ob[0] = (bf16)y0; ob[1] = (bf16)y1; ob[2] = (bf16)y2; ob[3] = (bf16)y3;
    ((bf16x4*)(obf + (size_t)row * 1024))[tid] = ob;
}

// =======================================================================
// GEMM: C[M,N] = A[M,K] @ Bt[N,K]^T (+bias, epilogue variants)
// 128x128 tile, BK=32, 4 waves of 64x64, mfma 16x16x32 bf16 (m97 structure)
// EPI 0: out bf16 permuted; N=3072 merged QKV -> qkv[which][b,h,s,d]
// EPI 1: out f32 = acc + bias + resid
// EPI 2: out bf16 = relu(acc + bias)
// =======================================================================
template <int EPI>
__global__ __launch_bounds__(256)
void gemm_bt(const bf16* __restrict__ A, const bf16* __restrict__ Bt,
             const float* __restrict__ bias, const float* __restrict__ resid,
             void* __restrict__ Cout, int M, int N, int K)
{
    __shared__ __attribute__((aligned(16))) bf16 a_lds[128 * 32];
    __shared__ __attribute__((aligned(16))) bf16 b_lds[128 * 32];
    const int tid = threadIdx.x;
    const int l = tid & 63, w = tid >> 6;
    const int lo = l & 15, hi = l >> 4;
    const int m0 = blockIdx.y * 128, n0 = blockIdx.x * 128;
    const int wrow = (w >> 1) * 64, wcol = (w & 1) * 64;
    const int srow = tid >> 2;            // 0..63
    const int scol = (tid & 3) * 8;       // 0,8,16,24

    f32x4 acc[4][4];
    #pragma unroll
    for (int i = 0; i < 4; ++i)
        #pragma unroll
        for (int j = 0; j < 4; ++j) acc[i][j] = f32x4{0.f, 0.f, 0.f, 0.f};

    const int nkt = K >> 5;
    for (int kt = 0; kt < nkt; ++kt) {
        __syncthreads();   // previous iter's reads done before overwrite
        const bf16* ag = A  + (size_t)(m0 + srow) * K + kt * 32 + scol;
        const bf16* bg = Bt + (size_t)(n0 + srow) * K + kt * 32 + scol;
        gld_lds16(ag,                  &a_lds[srow * 32 + scol]);
        gld_lds16(ag + (size_t)64 * K, &a_lds[(64 + srow) * 32 + scol]);
        gld_lds16(bg,                  &b_lds[srow * 32 + scol]);
        gld_lds16(bg + (size_t)64 * K, &b_lds[(64 + srow) * 32 + scol]);
        asm volatile("s_waitcnt vmcnt(0)" ::: "memory");
        __syncthreads();

        bf16x8 af[4], bfr[4];
        #pragma unroll
        for (int m = 0; m < 4; ++m)
            af[m] = *(const bf16x8*)&a_lds[(wrow + m * 16 + lo) * 32 + hi * 8];
        #pragma unroll
        for (int n = 0; n < 4; ++n)
            bfr[n] = *(const bf16x8*)&b_lds[(wcol + n * 16 + lo) * 32 + hi * 8];
        #pragma unroll
        for (int m = 0; m < 4; ++m)
            #pragma unroll
            for (int n = 0; n < 4; ++n)
                acc[m][n] = __builtin_amdgcn_mfma_f32_16x16x32_bf16(af[m], bfr[n], acc[m][n], 0, 0, 0);
    }

    // epilogue: C row = m0+wrow+m*16+hi*4+r, col = n0+wcol+n*16+lo
    #pragma unroll
    for (int m = 0; m < 4; ++m) {
        const int Rbase = m0 + wrow + m * 16 + hi * 4;
        #pragma unroll
        for (int n = 0; n < 4; ++n) {
            const int Cc = n0 + wcol + n * 16 + lo;
            const float bv = bias[Cc];
            #pragma unroll
            for (int r = 0; r < 4; ++r) {
                const int Rr = Rbase + r;
                float vv = acc[m][n][r] + bv;
                if (EPI == 0) {
                    const int b_ = Rr >> 10, s_ = Rr & 1023;
                    const int which = Cc >> 10;          // 0=q 1=k 2=v
                    const int cc = Cc & 1023;
                    const int h_ = cc >> 6, d_ = cc & 63;
                    ((bf16*)Cout)[(size_t)which * ((size_t)MROWS * 1024) +
                                  (((size_t)(b_ * 16 + h_) * 1024 + s_) << 6) + d_] = (bf16)vv;
                } else if (EPI == 1) {
                    vv += resid[(size_t)Rr * N + Cc];
                    ((float*)Cout)[(size_t)Rr * N + Cc] = vv;
                } else {
                    vv = fmaxf(vv, 0.f);
                    ((bf16*)Cout)[(size_t)Rr * N + Cc] = (bf16)vv;
                }
            }
        }
    }
}

// =======================================================================
// Flash attention. 1D grid 2048 blocks, XCD-swizzled; 4 waves x 16 q-rows.
// q,k,v: bf16 [b,h,s,d]. mask: bit-packed u64 [b,s,16]. ctx: bf16 [b,s,h,d].
// V^T staged in LDS with col XOR-swizzle: (d,kv) at [d][kv ^ (((d>>3)&7)<<3)]
// =======================================================================
__global__ __launch_bounds__(256)
void attn_kernel(const bf16* __restrict__ q, const bf16* __restrict__ k,
                 const bf16* __restrict__ v,
                 const unsigned long long* __restrict__ mbits,
                 bf16* __restrict__ ctx)
{
    __shared__ __attribute__((aligned(16))) bf16 q_lds[64][72];
    __shared__ __attribute__((aligned(16))) bf16 k_lds[64][72];
    __shared__ __attribute__((aligned(16))) bf16 vt_lds[64][72];   // [d][kvS]
    __shared__ __attribute__((aligned(16))) bf16 p_lds[4][16][72];

    const int id = blockIdx.x;
    const int swz = (id & 7) * 256 + (id >> 3);   // XCD r -> batch r contiguous
    const int qt = swz & 15;
    const int bh = swz >> 4;
    const int hh = bh & 15, bb = bh >> 4;
    const int tid = threadIdx.x;
    const int w = tid >> 6, l = tid & 63;
    const int lo = l & 15, hi = l >> 4;

    {   // stage Q tile [64][64]
        const bf16* qg = q + ((size_t)bh * SEQ + qt * 64) * D_HEAD;
        #pragma unroll
        for (int i = 0; i < 2; ++i) {
            const int e = (i * 256 + tid) * 8;
            const int r = e >> 6, c = e & 63;
            *(uint4*)&q_lds[r][c] = *(const uint4*)(qg + r * 64 + c);
        }
    }

    f32x4 oacc[4];
    float m_r[4], l_r[4];
    #pragma unroll
    for (int i = 0; i < 4; ++i) {
        oacc[i] = f32x4{0.f, 0.f, 0.f, 0.f};
        m_r[i] = -__builtin_inff();
        l_r[i] = 0.f;
    }

    for (int kt = 0; kt < 16; ++kt) {
        __syncthreads();
        const bf16* kg = k + ((size_t)bh * SEQ + kt * 64) * D_HEAD;
        const bf16* vg = v + ((size_t)bh * SEQ + kt * 64) * D_HEAD;
        #pragma unroll
        for (int i = 0; i < 2; ++i) {
            const int e = (i * 256 + tid) * 8;
            const int r = e >> 6, c = e & 63;
            *(uint4*)&k_lds[r][c] = *(const uint4*)(kg + r * 64 + c);
            uint4 tv = *(const uint4*)(vg + r * 64 + c);
            const bf16* pv = (const bf16*)&tv;
            const int colS = r ^ (((c >> 3) & 7) << 3);   // bank swizzle
            #pragma unroll
            for (int j = 0; j < 8; ++j) vt_lds[c + j][colS] = pv[j];
        }
        // mask bits for this wave's 4 q-rows (one u64 covers the 64 kv cols)
        unsigned long long mb[4];
        #pragma unroll
        for (int r = 0; r < 4; ++r) {
            const int qrow = qt * 64 + w * 16 + hi * 4 + r;
            mb[r] = mbits[((((size_t)bb << 10) | qrow) << 4) + kt];
        }
        __syncthreads();

        // S = Q K^T for this wave's 16 rows x 64 cols
        f32x4 sf[4];
        #pragma unroll
        for (int ct = 0; ct < 4; ++ct) {
            f32x4 sa = f32x4{0.f, 0.f, 0.f, 0.f};
            #pragma unroll
            for (int kk = 0; kk < 2; ++kk) {
                bf16x8 a   = *(const bf16x8*)&q_lds[w * 16 + lo][kk * 32 + hi * 8];
                bf16x8 bfr = *(const bf16x8*)&k_lds[ct * 16 + lo][kk * 32 + hi * 8];
                sa = __builtin_amdgcn_mfma_f32_16x16x32_bf16(a, bfr, sa, 0, 0, 0);
            }
            sf[ct] = sa;
        }

        // scale + mask + online softmax (row = w*16 + hi*4 + r, col = ct*16 + lo)
        float pm[4];
        #pragma unroll
        for (int r = 0; r < 4; ++r) {
            #pragma unroll
            for (int ct = 0; ct < 4; ++ct) {
                float sv = sf[ct][r] * 0.125f;
                if ((mb[r] >> (ct * 16 + lo)) & 1ull) sv = -__builtin_inff();
                sf[ct][r] = sv;
            }
            float t0 = fmaxf(fmaxf(sf[0][r], sf[1][r]), fmaxf(sf[2][r], sf[3][r]));
            #pragma unroll
            for (int off = 1; off < 16; off <<= 1) t0 = fmaxf(t0, __shfl_xor(t0, off));
            pm[r] = t0;
        }
        float scl[4];
        #pragma unroll
        for (int r = 0; r < 4; ++r) {
            const float mn = fmaxf(m_r[r], pm[r]);
            scl[r] = __expf(m_r[r] - mn);
            m_r[r] = mn;
            float acc_s = 0.f;
            #pragma unroll
            for (int ct = 0; ct < 4; ++ct) {
                const float p = __expf(sf[ct][r] - mn);
                sf[ct][r] = p;
                acc_s += p;
            }
            #pragma unroll
            for (int off = 1; off < 16; off <<= 1) acc_s += __shfl_xor(acc_s, off);
            l_r[r] = l_r[r] * scl[r] + acc_s;
        }
        #pragma unroll
        for (int n = 0; n < 4; ++n)
            #pragma unroll
            for (int r = 0; r < 4; ++r) oacc[n][r] *= scl[r];

        // P -> LDS (per-wave private)
        #pragma unroll
        for (int ct = 0; ct < 4; ++ct)
            #pragma unroll
            for (int r = 0; r < 4; ++r)
                p_lds[w][hi * 4 + r][ct * 16 + lo] = (bf16)sf[ct][r];
        asm volatile("s_waitcnt lgkmcnt(0)" ::: "memory");

        // O += P @ V   (V^T rows read through the XOR swizzle)
        #pragma unroll
        for (int n = 0; n < 4; ++n) {
            const int g = (((n * 16 + lo) >> 3) & 7) << 3;
            #pragma unroll
            for (int kk = 0; kk < 2; ++kk) {
                bf16x8 a   = *(const bf16x8*)&p_lds[w][lo][kk * 32 + hi * 8];
                bf16x8 bfr = *(const bf16x8*)&vt_lds[n * 16 + lo][(kk * 32 + hi * 8) ^ g];
                oacc[n] = __builtin_amdgcn_mfma_f32_16x16x32_bf16(a, bfr, oacc[n], 0, 0, 0);
            }
        }
    }

    // epilogue: ctx[b, s, h, d] = O / l
    #pragma unroll
    for (int r = 0; r < 4; ++r) {
        const float inv = 1.f / l_r[r];
        const size_t srow = (size_t)bb * SEQ + qt * 64 + w * 16 + hi * 4 + r;
        const size_t base = (srow * N_HEADS + hh) * D_HEAD;
        #pragma unroll
        for (int n = 0; n < 4; ++n)
            ctx[base + n * 16 + lo] = (bf16)(oacc[n][r] * inv);
    }
}

// =======================================================================
extern "C" void kernel_launch(void* const* d_in, const int* in_sizes, int n_in,
                              void* d_out, int out_size, void* d_ws, size_t ws_size,
                              hipStream_t stream)
{
    const float* x      = (const float*)d_in[0];
    const unsigned char* mask = (const unsigned char*)d_in[1];
    const float* gamma1 = (const float*)d_in[2];
    const float* beta1  = (const float*)d_in[3];
    const float* Wq     = (const float*)d_in[4];
    const float* bq     = (const float*)d_in[5];
    const float* Wk     = (const float*)d_in[6];
    const float* bk     = (const float*)d_in[7];
    const float* Wv     = (const float*)d_in[8];
    const float* bv     = (const float*)d_in[9];
    const float* Wo     = (const float*)d_in[10];
    const float* bo     = (const float*)d_in[11];
    const float* gamma2 = (const float*)d_in[12];
    const float* beta2  = (const float*)d_in[13];
    const float* W1     = (const float*)d_in[14];
    const float* b1     = (const float*)d_in[15];
    const float* W2     = (const float*)d_in[16];
    const float* b2     = (const float*)d_in[17];

    char* ws = (char*)d_ws;
    const size_t MB = 1u << 20;
    bf16* wqkv = (bf16*)(ws + 0 * MB);    // [3072][1024] bf16 (6MB)
    bf16* wot  = (bf16*)(ws + 6 * MB);    // [1024][1024] (2MB)
    bf16* w1t  = (bf16*)(ws + 8 * MB);    // [4096][1024] (8MB)
    bf16* w2t  = (bf16*)(ws + 16 * MB);   // [1024][4096] (8MB), written AFTER attn
    unsigned long long* mbits = (unsigned long long*)(ws + 16 * MB); // 1MB, dead before w2t
    float* bqkv = (float*)(ws + 17 * MB); // 12KB, dead before w2t
    bf16* xn1b = (bf16*)(ws + 24 * MB);   // [8192][1024] (16MB)
    float* xn1f = (float*)(ws + 40 * MB); // (32MB)
    bf16* qkv  = (bf16*)(ws + 72 * MB);   // [3][b,h,s,d] (48MB)
    bf16* ctx  = (bf16*)(ws + 120 * MB);  // [b,s,h,d] (16MB)
    bf16* hbuf = (bf16*)(ws + 72 * MB);   // [8192][4096] (64MB) aliases qkv+ctx (dead)
    bf16* xn2b = (bf16*)(ws + 136 * MB);  // (16MB)
    float* xn2f = (float*)(ws + 152 * MB);// (32MB) -> total 184MB
    float* x2f = (float*)d_out;           // reuse d_out as x2 scratch

    // weights -> bf16 transposed (W2 deferred: its slot holds mbits/bqkv now)
    wconv_t<<<dim3(32, 32),  256, 0, stream>>>(Wq, wqkv,               1024, 1024);
    wconv_t<<<dim3(32, 32),  256, 0, stream>>>(Wk, wqkv + 1024 * 1024, 1024, 1024);
    wconv_t<<<dim3(32, 32),  256, 0, stream>>>(Wv, wqkv + 2048 * 1024, 1024, 1024);
    wconv_t<<<dim3(32, 32),  256, 0, stream>>>(Wo, wot, 1024, 1024);
    wconv_t<<<dim3(128, 32), 256, 0, stream>>>(W1, w1t, 1024, 4096);
    bconcat<<<12, 256, 0, stream>>>(bq, bk, bv, bqkv);
    mask_pack<<<32768, 256, 0, stream>>>(mask, mbits);

    // xn1 = LN1(x)
    ln_kernel<<<MROWS, 256, 0, stream>>>(x, gamma1, beta1, xn1b, xn1f);

    // merged q,k,v projection: [8192,1024] @ [1024,3072]
    gemm_bt<0><<<dim3(24, 64), 256, 0, stream>>>(xn1b, wqkv, bqkv, nullptr, qkv, MROWS, 3072, 1024);

    // attention
    attn_kernel<<<2048, 256, 0, stream>>>(qkv, qkv + (size_t)MROWS * 1024,
                                          qkv + (size_t)2 * MROWS * 1024, mbits, ctx);

    // W2 convert now (slot shared with mbits/bqkv, both dead after attn/QKV)
    wconv_t<<<dim3(32, 128), 256, 0, stream>>>(W2, w2t, 4096, 1024);

    // x2 = xn1 + ctx @ Wo + bo   (into d_out as scratch)
    gemm_bt<1><<<dim3(8, 64), 256, 0, stream>>>(ctx, wot, bo, xn1f, x2f, MROWS, 1024, 1024);

    // xn2 = LN2(x2)
    ln_kernel<<<MROWS, 256, 0, stream>>>(x2f, gamma2, beta2, xn2b, xn2f);

    // h = relu(xn2 @ W1 + b1)
    gemm_bt<2><<<dim3(32, 64), 256, 0, stream>>>(xn2b, w1t, b1, nullptr, hbuf, MROWS, 4096, 1024);

    // out = xn2 + h @ W2 + b2
    gemm_bt<1><<<dim3(8, 64), 256, 0, stream>>>(hbuf, w2t, b2, xn2f, (float*)d_out, MROWS, 1024, 4096);
}

// Round 4
// 634.057 us; speedup vs baseline: 1.1010x; 1.0425x over previous
//
#include <hip/hip_runtime.h>
#include <hip/hip_bf16.h>

typedef __bf16 bf16;
typedef __bf16 bf16x8 __attribute__((ext_vector_type(8)));
typedef __bf16 bf16x4 __attribute__((ext_vector_type(4)));
typedef float  f32x4  __attribute__((ext_vector_type(4)));

#define N_HEADS 16
#define D_HEAD  64
#define SEQ     1024
#define BATCH   8
#define MROWS   (BATCH * SEQ)   // 8192

// ---- async global->LDS 16B (per-lane lds ptr = wave base + lane*16) ----
__device__ __forceinline__ void gld_lds16(const void* g, void* l) {
    __builtin_amdgcn_global_load_lds(
        (const __attribute__((address_space(1))) void*)g,
        (__attribute__((address_space(3))) void*)l, 16, 0, 0);
}

// =======================================================================
// Weight convert + transpose: W f32 [K][N] -> Wt bf16 [N][K]
// =======================================================================
__global__ __launch_bounds__(256)
void wconv_t(const float* __restrict__ W, bf16* __restrict__ Wt, int K, int N)
{
    __shared__ float tile[32][33];
    const int tx = threadIdx.x & 31, ty = threadIdx.x >> 5;   // 32 x 8
    const int nb = blockIdx.x * 32, kb = blockIdx.y * 32;
    #pragma unroll
    for (int i = 0; i < 4; ++i)
        tile[ty + i * 8][tx] = W[(size_t)(kb + ty + i * 8) * N + nb + tx];
    __syncthreads();
    #pragma unroll
    for (int i = 0; i < 4; ++i)
        Wt[(size_t)(nb + ty + i * 8) * K + kb + tx] = (bf16)tile[tx][ty + i * 8];
}

// =======================================================================
// Bias concat: bqkv[0:1024)=bq, [1024:2048)=bk, [2048:3072)=bv
// =======================================================================
__global__ __launch_bounds__(256)
void bconcat(const float* __restrict__ bq, const float* __restrict__ bk,
             const float* __restrict__ bv, float* __restrict__ o)
{
    const int i = blockIdx.x * 256 + threadIdx.x;
    if (i < 1024)       o[i] = bq[i];
    else if (i < 2048)  o[i] = bk[i - 1024];
    else if (i < 3072)  o[i] = bv[i - 2048];
}

// =======================================================================
// Mask pack: bool bytes [B,S,S] -> bit mask u64 [B,S,S/64]
// =======================================================================
__global__ __launch_bounds__(256)
void mask_pack(const unsigned char* __restrict__ m,
               unsigned long long* __restrict__ bits)
{
    const int i = blockIdx.x * 256 + threadIdx.x;
    unsigned long long b = __ballot(m[i] != 0);
    if ((threadIdx.x & 63) == 0) bits[i >> 6] = b;
}

// =======================================================================
// LayerNorm over last dim (1024). One block per row. Writes bf16 + f32.
// =======================================================================
__global__ __launch_bounds__(256)
void ln_kernel(const float* __restrict__ x, const float* __restrict__ g,
               const float* __restrict__ b, bf16* __restrict__ obf,
               float* __restrict__ of)
{
    const int row = blockIdx.x;
    const int tid = threadIdx.x;
    const float4 v = ((const float4*)(x + (size_t)row * 1024))[tid];
    float s  = v.x + v.y + v.z + v.w;
    float sq = v.x * v.x + v.y * v.y + v.z * v.z + v.w * v.w;
    #pragma unroll
    for (int off = 32; off; off >>= 1) {
        s  += __shfl_down(s, off);
        sq += __shfl_down(sq, off);
    }
    __shared__ float red[8];
    const int wid = tid >> 6, lid = tid & 63;
    if (lid == 0) { red[wid] = s; red[4 + wid] = sq; }
    __syncthreads();
    if (tid == 0) {
        float ts = red[0] + red[1] + red[2] + red[3];
        float tq = red[4] + red[5] + red[6] + red[7];
        float mean = ts * (1.f / 1024.f);
        float var  = tq * (1.f / 1024.f) - mean * mean;
        red[0] = mean;
        red[1] = rsqrtf(var + 1e-6f);
    }
    __syncthreads();
    const float mean = red[0], rstd = red[1];
    const float4 gg = ((const float4*)g)[tid];
    const float4 bb = ((const float4*)b)[tid];
    float y0 = (v.x - mean) * rstd * gg.x + bb.x;
    float y1 = (v.y - mean) * rstd * gg.y + bb.y;
    float y2 = (v.z - mean) * rstd * gg.z + bb.z;
    float y3 = (v.w - mean) * rstd * gg.w + bb.w;
    float4 o; o.x = y0; o.y = y1; o.z = y2; o.w = y3;
    ((float4*)(of + (size_t)row * 1024))[tid] = o;
    bf16x4 ob; ob[0] = (bf16)y0; ob[1] = (bf16)y1; ob[2] = (bf16)y2; ob[3] = (bf16)y3;
    ((bf16x4*)(obf + (size_t)row * 1024))[tid] = ob;
}

// =======================================================================
// GEMM: C[M,N] = A[M,K] @ Bt[N,K]^T (+bias, epilogue variants)
// 128x128 tile, BK=64, 4 waves of 64x64, mfma 16x16x32 bf16.
// 1D grid, bijective XCD swizzle (nwg % 8 == 0 guaranteed by launches).
// LDS linear [128][64]; XOR chunk swizzle done on the GLOBAL source addr
// (m173/m201 pattern) and re-applied on ds_read -> 8 dwords/bank optimal.
// EPI 0: out bf16 permuted; N=3072 merged QKV -> qkv[which][b,h,s,d]
// EPI 1: out f32 = acc + bias + resid
// EPI 2: out bf16 = relu(acc + bias)
// =======================================================================
template <int EPI>
__global__ __launch_bounds__(256)
void gemm_bt(const bf16* __restrict__ A, const bf16* __restrict__ Bt,
             const float* __restrict__ bias, const float* __restrict__ resid,
             void* __restrict__ Cout, int M, int N, int K, int nbx)
{
    __shared__ __attribute__((aligned(16))) bf16 a_lds[128 * 64];
    __shared__ __attribute__((aligned(16))) bf16 b_lds[128 * 64];
    const int tid = threadIdx.x;
    const int l = tid & 63, w = tid >> 6;
    const int lo = l & 15, hi = l >> 4;

    // bijective XCD swizzle: nwg = gridDim.x, 8 | nwg
    const int nwg = gridDim.x;
    const int nid = (blockIdx.x & 7) * (nwg >> 3) + (blockIdx.x >> 3);
    const int bx = nid % nbx, by = nid / nbx;
    const int m0 = by * 128, n0 = bx * 128;

    const int wrow = (w >> 1) * 64, wcol = (w & 1) * 64;
    const int srow = tid >> 3;                 // 0..31
    const int c8   = tid & 7;                  // lds chunk
    const int c8g  = c8 ^ (srow & 7);          // swizzled global chunk

    f32x4 acc[4][4];
    #pragma unroll
    for (int i = 0; i < 4; ++i)
        #pragma unroll
        for (int j = 0; j < 4; ++j) acc[i][j] = f32x4{0.f, 0.f, 0.f, 0.f};

    const int nkt = K >> 6;
    for (int kt = 0; kt < nkt; ++kt) {
        __syncthreads();   // previous iter's reads done before overwrite
        const int kc = kt * 64 + c8g * 8;
        #pragma unroll
        for (int blk = 0; blk < 4; ++blk) {
            const int row = blk * 32 + srow;   // row&7 == srow&7
            gld_lds16(A  + (size_t)(m0 + row) * K + kc, &a_lds[row * 64 + c8 * 8]);
            gld_lds16(Bt + (size_t)(n0 + row) * K + kc, &b_lds[row * 64 + c8 * 8]);
        }
        asm volatile("s_waitcnt vmcnt(0)" ::: "memory");
        __syncthreads();

        #pragma unroll
        for (int kk2 = 0; kk2 < 2; ++kk2) {
            bf16x8 af[4], bfr[4];
            #pragma unroll
            for (int m = 0; m < 4; ++m) {
                const int row = wrow + m * 16 + lo;
                const int ch = ((kk2 * 4 + hi) ^ (lo & 7)) << 3;
                af[m] = *(const bf16x8*)&a_lds[row * 64 + ch];
            }
            #pragma unroll
            for (int n = 0; n < 4; ++n) {
                const int row = wcol + n * 16 + lo;
                const int ch = ((kk2 * 4 + hi) ^ (lo & 7)) << 3;
                bfr[n] = *(const bf16x8*)&b_lds[row * 64 + ch];
            }
            #pragma unroll
            for (int m = 0; m < 4; ++m)
                #pragma unroll
                for (int n = 0; n < 4; ++n)
                    acc[m][n] = __builtin_amdgcn_mfma_f32_16x16x32_bf16(af[m], bfr[n], acc[m][n], 0, 0, 0);
        }
    }

    // epilogue: C row = m0+wrow+m*16+hi*4+r, col = n0+wcol+n*16+lo
    #pragma unroll
    for (int m = 0; m < 4; ++m) {
        const int Rbase = m0 + wrow + m * 16 + hi * 4;
        #pragma unroll
        for (int n = 0; n < 4; ++n) {
            const int Cc = n0 + wcol + n * 16 + lo;
            const float bv = bias[Cc];
            #pragma unroll
            for (int r = 0; r < 4; ++r) {
                const int Rr = Rbase + r;
                float vv = acc[m][n][r] + bv;
                if (EPI == 0) {
                    const int b_ = Rr >> 10, s_ = Rr & 1023;
                    const int which = Cc >> 10;          // 0=q 1=k 2=v
                    const int cc = Cc & 1023;
                    const int h_ = cc >> 6, d_ = cc & 63;
                    ((bf16*)Cout)[(size_t)which * ((size_t)MROWS * 1024) +
                                  (((size_t)(b_ * 16 + h_) * 1024 + s_) << 6) + d_] = (bf16)vv;
                } else if (EPI == 1) {
                    vv += resid[(size_t)Rr * N + Cc];
                    ((float*)Cout)[(size_t)Rr * N + Cc] = vv;
                } else {
                    vv = fmaxf(vv, 0.f);
                    ((bf16*)Cout)[(size_t)Rr * N + Cc] = (bf16)vv;
                }
            }
        }
    }
}

// =======================================================================
// Flash attention. 1D grid 2048 blocks, XCD-swizzled; 4 waves x 16 q-rows.
// q,k,v: bf16 [b,h,s,d]. mask: bit-packed u64 [b,s,16]. ctx: bf16 [b,s,h,d].
// V^T staged in LDS with col XOR-swizzle: (d,kv) at [d][kv ^ (((d>>3)&7)<<3)]
// =======================================================================
__global__ __launch_bounds__(256)
void attn_kernel(const bf16* __restrict__ q, const bf16* __restrict__ k,
                 const bf16* __restrict__ v,
                 const unsigned long long* __restrict__ mbits,
                 bf16* __restrict__ ctx)
{
    __shared__ __attribute__((aligned(16))) bf16 q_lds[64][72];
    __shared__ __attribute__((aligned(16))) bf16 k_lds[64][72];
    __shared__ __attribute__((aligned(16))) bf16 vt_lds[64][72];   // [d][kvS]
    __shared__ __attribute__((aligned(16))) bf16 p_lds[4][16][72];

    const int id = blockIdx.x;
    const int swz = (id & 7) * 256 + (id >> 3);   // XCD r -> batch r contiguous
    const int qt = swz & 15;
    const int bh = swz >> 4;
    const int hh = bh & 15, bb = bh >> 4;
    const int tid = threadIdx.x;
    const int w = tid >> 6, l = tid & 63;
    const int lo = l & 15, hi = l >> 4;

    {   // stage Q tile [64][64]
        const bf16* qg = q + ((size_t)bh * SEQ + qt * 64) * D_HEAD;
        #pragma unroll
        for (int i = 0; i < 2; ++i) {
            const int e = (i * 256 + tid) * 8;
            const int r = e >> 6, c = e & 63;
            *(uint4*)&q_lds[r][c] = *(const uint4*)(qg + r * 64 + c);
        }
    }

    f32x4 oacc[4];
    float m_r[4], l_r[4];
    #pragma unroll
    for (int i = 0; i < 4; ++i) {
        oacc[i] = f32x4{0.f, 0.f, 0.f, 0.f};
        m_r[i] = -__builtin_inff();
        l_r[i] = 0.f;
    }

    for (int kt = 0; kt < 16; ++kt) {
        __syncthreads();
        const bf16* kg = k + ((size_t)bh * SEQ + kt * 64) * D_HEAD;
        const bf16* vg = v + ((size_t)bh * SEQ + kt * 64) * D_HEAD;
        #pragma unroll
        for (int i = 0; i < 2; ++i) {
            const int e = (i * 256 + tid) * 8;
            const int r = e >> 6, c = e & 63;
            *(uint4*)&k_lds[r][c] = *(const uint4*)(kg + r * 64 + c);
            uint4 tv = *(const uint4*)(vg + r * 64 + c);
            const bf16* pv = (const bf16*)&tv;
            const int colS = r ^ (((c >> 3) & 7) << 3);   // bank swizzle
            #pragma unroll
            for (int j = 0; j < 8; ++j) vt_lds[c + j][colS] = pv[j];
        }
        // mask bits for this wave's 4 q-rows (one u64 covers the 64 kv cols)
        unsigned long long mb[4];
        #pragma unroll
        for (int r = 0; r < 4; ++r) {
            const int qrow = qt * 64 + w * 16 + hi * 4 + r;
            mb[r] = mbits[((((size_t)bb << 10) | qrow) << 4) + kt];
        }
        __syncthreads();

        // S = Q K^T for this wave's 16 rows x 64 cols
        f32x4 sf[4];
        #pragma unroll
        for (int ct = 0; ct < 4; ++ct) {
            f32x4 sa = f32x4{0.f, 0.f, 0.f, 0.f};
            #pragma unroll
            for (int kk = 0; kk < 2; ++kk) {
                bf16x8 a   = *(const bf16x8*)&q_lds[w * 16 + lo][kk * 32 + hi * 8];
                bf16x8 bfr = *(const bf16x8*)&k_lds[ct * 16 + lo][kk * 32 + hi * 8];
                sa = __builtin_amdgcn_mfma_f32_16x16x32_bf16(a, bfr, sa, 0, 0, 0);
            }
            sf[ct] = sa;
        }

        // scale + mask + online softmax (row = w*16 + hi*4 + r, col = ct*16 + lo)
        float pm[4];
        #pragma unroll
        for (int r = 0; r < 4; ++r) {
            #pragma unroll
            for (int ct = 0; ct < 4; ++ct) {
                float sv = sf[ct][r] * 0.125f;
                if ((mb[r] >> (ct * 16 + lo)) & 1ull) sv = -__builtin_inff();
                sf[ct][r] = sv;
            }
            float t0 = fmaxf(fmaxf(sf[0][r], sf[1][r]), fmaxf(sf[2][r], sf[3][r]));
            #pragma unroll
            for (int off = 1; off < 16; off <<= 1) t0 = fmaxf(t0, __shfl_xor(t0, off));
            pm[r] = t0;
        }
        float scl[4];
        #pragma unroll
        for (int r = 0; r < 4; ++r) {
            const float mn = fmaxf(m_r[r], pm[r]);
            scl[r] = __expf(m_r[r] - mn);
            m_r[r] = mn;
            float acc_s = 0.f;
            #pragma unroll
            for (int ct = 0; ct < 4; ++ct) {
                const float p = __expf(sf[ct][r] - mn);
                sf[ct][r] = p;
                acc_s += p;
            }
            #pragma unroll
            for (int off = 1; off < 16; off <<= 1) acc_s += __shfl_xor(acc_s, off);
            l_r[r] = l_r[r] * scl[r] + acc_s;
        }
        #pragma unroll
        for (int n = 0; n < 4; ++n)
            #pragma unroll
            for (int r = 0; r < 4; ++r) oacc[n][r] *= scl[r];

        // P -> LDS (per-wave private)
        #pragma unroll
        for (int ct = 0; ct < 4; ++ct)
            #pragma unroll
            for (int r = 0; r < 4; ++r)
                p_lds[w][hi * 4 + r][ct * 16 + lo] = (bf16)sf[ct][r];
        asm volatile("s_waitcnt lgkmcnt(0)" ::: "memory");

        // O += P @ V   (V^T rows read through the XOR swizzle)
        #pragma unroll
        for (int n = 0; n < 4; ++n) {
            const int g = (((n * 16 + lo) >> 3) & 7) << 3;
            #pragma unroll
            for (int kk = 0; kk < 2; ++kk) {
                bf16x8 a   = *(const bf16x8*)&p_lds[w][lo][kk * 32 + hi * 8];
                bf16x8 bfr = *(const bf16x8*)&vt_lds[n * 16 + lo][(kk * 32 + hi * 8) ^ g];
                oacc[n] = __builtin_amdgcn_mfma_f32_16x16x32_bf16(a, bfr, oacc[n], 0, 0, 0);
            }
        }
    }

    // epilogue: ctx[b, s, h, d] = O / l
    #pragma unroll
    for (int r = 0; r < 4; ++r) {
        const float inv = 1.f / l_r[r];
        const size_t srow = (size_t)bb * SEQ + qt * 64 + w * 16 + hi * 4 + r;
        const size_t base = (srow * N_HEADS + hh) * D_HEAD;
        #pragma unroll
        for (int n = 0; n < 4; ++n)
            ctx[base + n * 16 + lo] = (bf16)(oacc[n][r] * inv);
    }
}

// =======================================================================
extern "C" void kernel_launch(void* const* d_in, const int* in_sizes, int n_in,
                              void* d_out, int out_size, void* d_ws, size_t ws_size,
                              hipStream_t stream)
{
    const float* x      = (const float*)d_in[0];
    const unsigned char* mask = (const unsigned char*)d_in[1];
    const float* gamma1 = (const float*)d_in[2];
    const float* beta1  = (const float*)d_in[3];
    const float* Wq     = (const float*)d_in[4];
    const float* bq     = (const float*)d_in[5];
    const float* Wk     = (const float*)d_in[6];
    const float* bk     = (const float*)d_in[7];
    const float* Wv     = (const float*)d_in[8];
    const float* bv     = (const float*)d_in[9];
    const float* Wo     = (const float*)d_in[10];
    const float* bo     = (const float*)d_in[11];
    const float* gamma2 = (const float*)d_in[12];
    const float* beta2  = (const float*)d_in[13];
    const float* W1     = (const float*)d_in[14];
    const float* b1     = (const float*)d_in[15];
    const float* W2     = (const float*)d_in[16];
    const float* b2     = (const float*)d_in[17];

    char* ws = (char*)d_ws;
    const size_t MB = 1u << 20;
    bf16* wqkv = (bf16*)(ws + 0 * MB);    // [3072][1024] bf16 (6MB)
    bf16* wot  = (bf16*)(ws + 6 * MB);    // [1024][1024] (2MB)
    bf16* w1t  = (bf16*)(ws + 8 * MB);    // [4096][1024] (8MB)
    bf16* w2t  = (bf16*)(ws + 16 * MB);   // [1024][4096] (8MB), written AFTER attn
    unsigned long long* mbits = (unsigned long long*)(ws + 16 * MB); // 1MB, dead before w2t
    float* bqkv = (float*)(ws + 17 * MB); // 12KB, dead before w2t
    bf16* xn1b = (bf16*)(ws + 24 * MB);   // [8192][1024] (16MB)
    float* xn1f = (float*)(ws + 40 * MB); // (32MB)
    bf16* qkv  = (bf16*)(ws + 72 * MB);   // [3][b,h,s,d] (48MB)
    bf16* ctx  = (bf16*)(ws + 120 * MB);  // [b,s,h,d] (16MB)
    bf16* hbuf = (bf16*)(ws + 72 * MB);   // [8192][4096] (64MB) aliases qkv+ctx (dead)
    bf16* xn2b = (bf16*)(ws + 136 * MB);  // (16MB)
    float* xn2f = (float*)(ws + 152 * MB);// (32MB) -> total 184MB
    float* x2f = (float*)d_out;           // reuse d_out as x2 scratch

    // weights -> bf16 transposed (W2 deferred: its slot holds mbits/bqkv now)
    wconv_t<<<dim3(32, 32),  256, 0, stream>>>(Wq, wqkv,               1024, 1024);
    wconv_t<<<dim3(32, 32),  256, 0, stream>>>(Wk, wqkv + 1024 * 1024, 1024, 1024);
    wconv_t<<<dim3(32, 32),  256, 0, stream>>>(Wv, wqkv + 2048 * 1024, 1024, 1024);
    wconv_t<<<dim3(32, 32),  256, 0, stream>>>(Wo, wot, 1024, 1024);
    wconv_t<<<dim3(128, 32), 256, 0, stream>>>(W1, w1t, 1024, 4096);
    bconcat<<<12, 256, 0, stream>>>(bq, bk, bv, bqkv);
    mask_pack<<<32768, 256, 0, stream>>>(mask, mbits);

    // xn1 = LN1(x)
    ln_kernel<<<MROWS, 256, 0, stream>>>(x, gamma1, beta1, xn1b, xn1f);

    // merged q,k,v projection: [8192,1024] @ [1024,3072]
    gemm_bt<0><<<24 * 64, 256, 0, stream>>>(xn1b, wqkv, bqkv, nullptr, qkv, MROWS, 3072, 1024, 24);

    // attention
    attn_kernel<<<2048, 256, 0, stream>>>(qkv, qkv + (size_t)MROWS * 1024,
                                          qkv + (size_t)2 * MROWS * 1024, mbits, ctx);

    // W2 convert now (slot shared with mbits/bqkv, both dead after attn/QKV)
    wconv_t<<<dim3(32, 128), 256, 0, stream>>>(W2, w2t, 4096, 1024);

    // x2 = xn1 + ctx @ Wo + bo   (into d_out as scratch)
    gemm_bt<1><<<8 * 64, 256, 0, stream>>>(ctx, wot, bo, xn1f, x2f, MROWS, 1024, 1024, 8);

    // xn2 = LN2(x2)
    ln_kernel<<<MROWS, 256, 0, stream>>>(x2f, gamma2, beta2, xn2b, xn2f);

    // h = relu(xn2 @ W1 + b1)
    gemm_bt<2><<<32 * 64, 256, 0, stream>>>(xn2b, w1t, b1, nullptr, hbuf, MROWS, 4096, 1024, 32);

    // out = xn2 + h @ W2 + b2
    gemm_bt<1><<<8 * 64, 256, 0, stream>>>(hbuf, w2t, b2, xn2f, (float*)d_out, MROWS, 1024, 4096, 8);
}

// Round 5
// 623.624 us; speedup vs baseline: 1.1195x; 1.0167x over previous
//
#include <hip/hip_runtime.h>
#include <hip/hip_bf16.h>

typedef __bf16 bf16;
typedef __bf16 bf16x8 __attribute__((ext_vector_type(8)));
typedef __bf16 bf16x4 __attribute__((ext_vector_type(4)));
typedef float  f32x4  __attribute__((ext_vector_type(4)));

#define N_HEADS 16
#define D_HEAD  64
#define SEQ     1024
#define BATCH   8
#define MROWS   (BATCH * SEQ)   // 8192

// ---- async global->LDS 16B (per-lane lds ptr = wave base + lane*16) ----
__device__ __forceinline__ void gld_lds16(const void* g, void* l) {
    __builtin_amdgcn_global_load_lds(
        (const __attribute__((address_space(1))) void*)g,
        (__attribute__((address_space(3))) void*)l, 16, 0, 0);
}

// =======================================================================
// Weight convert + transpose: W f32 [K][N] -> Wt bf16 [N][K]
// =======================================================================
__global__ __launch_bounds__(256)
void wconv_t(const float* __restrict__ W, bf16* __restrict__ Wt, int K, int N)
{
    __shared__ float tile[32][33];
    const int tx = threadIdx.x & 31, ty = threadIdx.x >> 5;   // 32 x 8
    const int nb = blockIdx.x * 32, kb = blockIdx.y * 32;
    #pragma unroll
    for (int i = 0; i < 4; ++i)
        tile[ty + i * 8][tx] = W[(size_t)(kb + ty + i * 8) * N + nb + tx];
    __syncthreads();
    #pragma unroll
    for (int i = 0; i < 4; ++i)
        Wt[(size_t)(nb + ty + i * 8) * K + kb + tx] = (bf16)tile[tx][ty + i * 8];
}

// =======================================================================
// Bias concat: bqkv[0:1024)=bq, [1024:2048)=bk, [2048:3072)=bv
// =======================================================================
__global__ __launch_bounds__(256)
void bconcat(const float* __restrict__ bq, const float* __restrict__ bk,
             const float* __restrict__ bv, float* __restrict__ o)
{
    const int i = blockIdx.x * 256 + threadIdx.x;
    if (i < 1024)       o[i] = bq[i];
    else if (i < 2048)  o[i] = bk[i - 1024];
    else if (i < 3072)  o[i] = bv[i - 2048];
}

// =======================================================================
// Mask pack: bool bytes [B,S,S] -> bit mask u64 [B,S,S/64]
// =======================================================================
__global__ __launch_bounds__(256)
void mask_pack(const unsigned char* __restrict__ m,
               unsigned long long* __restrict__ bits)
{
    const int i = blockIdx.x * 256 + threadIdx.x;
    unsigned long long b = __ballot(m[i] != 0);
    if ((threadIdx.x & 63) == 0) bits[i >> 6] = b;
}

// =======================================================================
// LayerNorm over last dim (1024). One block per row. Writes bf16 + f32.
// =======================================================================
__global__ __launch_bounds__(256)
void ln_kernel(const float* __restrict__ x, const float* __restrict__ g,
               const float* __restrict__ b, bf16* __restrict__ obf,
               float* __restrict__ of)
{
    const int row = blockIdx.x;
    const int tid = threadIdx.x;
    const float4 v = ((const float4*)(x + (size_t)row * 1024))[tid];
    float s  = v.x + v.y + v.z + v.w;
    float sq = v.x * v.x + v.y * v.y + v.z * v.z + v.w * v.w;
    #pragma unroll
    for (int off = 32; off; off >>= 1) {
        s  += __shfl_down(s, off);
        sq += __shfl_down(sq, off);
    }
    __shared__ float red[8];
    const int wid = tid >> 6, lid = tid & 63;
    if (lid == 0) { red[wid] = s; red[4 + wid] = sq; }
    __syncthreads();
    if (tid == 0) {
        float ts = red[0] + red[1] + red[2] + red[3];
        float tq = red[4] + red[5] + red[6] + red[7];
        float mean = ts * (1.f / 1024.f);
        float var  = tq * (1.f / 1024.f) - mean * mean;
        red[0] = mean;
        red[1] = rsqrtf(var + 1e-6f);
    }
    __syncthreads();
    const float mean = red[0], rstd = red[1];
    const float4 gg = ((const float4*)g)[tid];
    const float4 bb = ((const float4*)b)[tid];
    float y0 = (v.x - mean) * rstd * gg.x + bb.x;
    float y1 = (v.y - mean) * rstd * gg.y + bb.y;
    float y2 = (v.z - mean) * rstd * gg.z + bb.z;
    float y3 = (v.w - mean) * rstd * gg.w + bb.w;
    float4 o; o.x = y0; o.y = y1; o.z = y2; o.w = y3;
    ((float4*)(of + (size_t)row * 1024))[tid] = o;
    bf16x4 ob; ob[0] = (bf16)y0; ob[1] = (bf16)y1; ob[2] = (bf16)y2; ob[3] = (bf16)y3;
    ((bf16x4*)(obf + (size_t)row * 1024))[tid] = ob;
}

// =======================================================================
// GEMM: C[M,N] = A[M,K] @ Bt[N,K]^T (+bias, epilogue variants)
// 128x128 tile, BK=64, 4 waves of 64x64, mfma 16x16x32 bf16.
// 1D grid, bijective XCD swizzle; LDS linear + chunk-XOR swizzle via
// pre-swizzled global source (m173/m201 pattern).  [unchanged from r4]
// =======================================================================
template <int EPI>
__global__ __launch_bounds__(256)
void gemm_bt(const bf16* __restrict__ A, const bf16* __restrict__ Bt,
             const float* __restrict__ bias, const float* __restrict__ resid,
             void* __restrict__ Cout, int M, int N, int K, int nbx)
{
    __shared__ __attribute__((aligned(16))) bf16 a_lds[128 * 64];
    __shared__ __attribute__((aligned(16))) bf16 b_lds[128 * 64];
    const int tid = threadIdx.x;
    const int l = tid & 63, w = tid >> 6;
    const int lo = l & 15, hi = l >> 4;

    const int nwg = gridDim.x;
    const int nid = (blockIdx.x & 7) * (nwg >> 3) + (blockIdx.x >> 3);
    const int bx = nid % nbx, by = nid / nbx;
    const int m0 = by * 128, n0 = bx * 128;

    const int wrow = (w >> 1) * 64, wcol = (w & 1) * 64;
    const int srow = tid >> 3;                 // 0..31
    const int c8   = tid & 7;                  // lds chunk
    const int c8g  = c8 ^ (srow & 7);          // swizzled global chunk

    f32x4 acc[4][4];
    #pragma unroll
    for (int i = 0; i < 4; ++i)
        #pragma unroll
        for (int j = 0; j < 4; ++j) acc[i][j] = f32x4{0.f, 0.f, 0.f, 0.f};

    const int nkt = K >> 6;
    for (int kt = 0; kt < nkt; ++kt) {
        __syncthreads();
        const int kc = kt * 64 + c8g * 8;
        #pragma unroll
        for (int blk = 0; blk < 4; ++blk) {
            const int row = blk * 32 + srow;   // row&7 == srow&7
            gld_lds16(A  + (size_t)(m0 + row) * K + kc, &a_lds[row * 64 + c8 * 8]);
            gld_lds16(Bt + (size_t)(n0 + row) * K + kc, &b_lds[row * 64 + c8 * 8]);
        }
        asm volatile("s_waitcnt vmcnt(0)" ::: "memory");
        __syncthreads();

        #pragma unroll
        for (int kk2 = 0; kk2 < 2; ++kk2) {
            bf16x8 af[4], bfr[4];
            #pragma unroll
            for (int m = 0; m < 4; ++m) {
                const int row = wrow + m * 16 + lo;
                const int ch = ((kk2 * 4 + hi) ^ (lo & 7)) << 3;
                af[m] = *(const bf16x8*)&a_lds[row * 64 + ch];
            }
            #pragma unroll
            for (int n = 0; n < 4; ++n) {
                const int row = wcol + n * 16 + lo;
                const int ch = ((kk2 * 4 + hi) ^ (lo & 7)) << 3;
                bfr[n] = *(const bf16x8*)&b_lds[row * 64 + ch];
            }
            #pragma unroll
            for (int m = 0; m < 4; ++m)
                #pragma unroll
                for (int n = 0; n < 4; ++n)
                    acc[m][n] = __builtin_amdgcn_mfma_f32_16x16x32_bf16(af[m], bfr[n], acc[m][n], 0, 0, 0);
        }
    }

    #pragma unroll
    for (int m = 0; m < 4; ++m) {
        const int Rbase = m0 + wrow + m * 16 + hi * 4;
        #pragma unroll
        for (int n = 0; n < 4; ++n) {
            const int Cc = n0 + wcol + n * 16 + lo;
            const float bv = bias[Cc];
            #pragma unroll
            for (int r = 0; r < 4; ++r) {
                const int Rr = Rbase + r;
                float vv = acc[m][n][r] + bv;
                if (EPI == 0) {
                    const int b_ = Rr >> 10, s_ = Rr & 1023;
                    const int which = Cc >> 10;          // 0=q 1=k 2=v
                    const int cc = Cc & 1023;
                    const int h_ = cc >> 6, d_ = cc & 63;
                    ((bf16*)Cout)[(size_t)which * ((size_t)MROWS * 1024) +
                                  (((size_t)(b_ * 16 + h_) * 1024 + s_) << 6) + d_] = (bf16)vv;
                } else if (EPI == 1) {
                    vv += resid[(size_t)Rr * N + Cc];
                    ((float*)Cout)[(size_t)Rr * N + Cc] = vv;
                } else {
                    vv = fmaxf(vv, 0.f);
                    ((bf16*)Cout)[(size_t)Rr * N + Cc] = (bf16)vv;
                }
            }
        }
    }
}

// =======================================================================
// Flash attention, swapped-QK^T (S^T) structure.
// Grid 2048 XCD-swizzled; 4 waves x 16 q-rows; KV tile 64, dbuf + reg
// prefetch, 1 barrier/kt.  Each lane owns q-row (w*16+lo): softmax reduce
// = 15 in-reg + 2 shfl_xor.  Q frags hoisted to regs (identical layout as
// A- or B-operand).  P packed bf16x4 writes into per-wave region of
// qp_lds (aliased with the Q staging buffer).  T13 defer-max (THR=8).
// =======================================================================
__global__ __launch_bounds__(256)
void attn_kernel(const bf16* __restrict__ q, const bf16* __restrict__ k,
                 const bf16* __restrict__ v,
                 const unsigned long long* __restrict__ mbits,
                 bf16* __restrict__ ctx)
{
    __shared__ __attribute__((aligned(16))) bf16 k_lds[2][64][72];
    __shared__ __attribute__((aligned(16))) bf16 vt_lds[2][64][72];  // [d][kvS]
    __shared__ __attribute__((aligned(16))) bf16 qp_lds[64][72];     // Q stage, then P

    const int id = blockIdx.x;
    const int swz = (id & 7) * 256 + (id >> 3);   // XCD -> batch contiguous
    const int qt = swz & 15;
    const int bh = swz >> 4;
    const int hh = bh & 15, bb = bh >> 4;
    const int tid = threadIdx.x;
    const int w = tid >> 6, l = tid & 63;
    const int lo = l & 15, hi = l >> 4;

    const bf16* qg = q + ((size_t)bh * SEQ + qt * 64) * D_HEAD;
    const bf16* kg = k + (size_t)bh * SEQ * D_HEAD;
    const bf16* vg = v + (size_t)bh * SEQ * D_HEAD;

    // ---- stage Q tile [64][64] into qp_lds; prefetch K0/V0 into regs ----
    uint4 kreg[2], vreg[2];
    #pragma unroll
    for (int i = 0; i < 2; ++i) {
        const int e = (i * 256 + tid) * 8;
        const int r = e >> 6, c = e & 63;
        *(uint4*)&qp_lds[r][c] = *(const uint4*)(qg + r * 64 + c);
        kreg[i] = *(const uint4*)(kg + r * 64 + c);
        vreg[i] = *(const uint4*)(vg + r * 64 + c);
    }
    __syncthreads();   // Q visible

    // ---- hoist Q fragments (layout identical for A/B operand roles) ----
    bf16x8 qf[2];
    #pragma unroll
    for (int kk = 0; kk < 2; ++kk)
        qf[kk] = *(const bf16x8*)&qp_lds[w * 16 + lo][kk * 32 + hi * 8];

    // ---- write K0/V0 to buf 0 (V transposed + XOR-swizzled) ----
    #pragma unroll
    for (int i = 0; i < 2; ++i) {
        const int e = (i * 256 + tid) * 8;
        const int r = e >> 6, c = e & 63;
        *(uint4*)&k_lds[0][r][c] = kreg[i];
        const bf16* pv = (const bf16*)&vreg[i];
        const int colS = r ^ (((c >> 3) & 7) << 3);
        #pragma unroll
        for (int j = 0; j < 8; ++j) vt_lds[0][c + j][colS] = pv[j];
    }

    f32x4 oacc[4];
    #pragma unroll
    for (int i = 0; i < 4; ++i) oacc[i] = f32x4{0.f, 0.f, 0.f, 0.f};
    float m_q = -__builtin_inff(), l_q = 0.f;

    const int qrow = qt * 64 + w * 16 + lo;
    const size_t mbase = (((size_t)bb << 10) | (size_t)qrow) << 4;

    __syncthreads();   // buf0 visible (also covers qf reads ordering w/ p writes)

    for (int kt = 0; kt < 16; ++kt) {
        const int cur = kt & 1, nxt = cur ^ 1;
        if (kt < 15) {   // prefetch kt+1 into regs (latency hides under compute)
            const bf16* kgn = kg + (size_t)(kt + 1) * 64 * D_HEAD;
            const bf16* vgn = vg + (size_t)(kt + 1) * 64 * D_HEAD;
            #pragma unroll
            for (int i = 0; i < 2; ++i) {
                const int e = (i * 256 + tid) * 8;
                const int r = e >> 6, c = e & 63;
                kreg[i] = *(const uint4*)(kgn + r * 64 + c);
                vreg[i] = *(const uint4*)(vgn + r * 64 + c);
            }
        }
        const unsigned long long mb = mbits[mbase + kt];

        // S^T = mfma(K, Q): st[ct][r] = S[q=lo][kv=ct*16+hi*4+r]
        f32x4 st[4];
        #pragma unroll
        for (int ct = 0; ct < 4; ++ct) {
            f32x4 sa = f32x4{0.f, 0.f, 0.f, 0.f};
            #pragma unroll
            for (int kk = 0; kk < 2; ++kk) {
                bf16x8 kf = *(const bf16x8*)&k_lds[cur][ct * 16 + lo][kk * 32 + hi * 8];
                sa = __builtin_amdgcn_mfma_f32_16x16x32_bf16(kf, qf[kk], sa, 0, 0, 0);
            }
            st[ct] = sa;
        }

        // scale + mask (bit kv = ct*16+hi*4+r of this q-row's u64)
        #pragma unroll
        for (int ct = 0; ct < 4; ++ct)
            #pragma unroll
            for (int r = 0; r < 4; ++r) {
                float sv = st[ct][r] * 0.125f;
                if ((mb >> (ct * 16 + hi * 4 + r)) & 1ull) sv = -__builtin_inff();
                st[ct][r] = sv;
            }

        // kv-tile max for this q-row: 15 in-reg + 2 shfl
        float tmax = st[0][0];
        #pragma unroll
        for (int ct = 0; ct < 4; ++ct)
            #pragma unroll
            for (int r = 0; r < 4; ++r)
                if (ct + r) tmax = fmaxf(tmax, st[ct][r]);
        tmax = fmaxf(tmax, __shfl_xor(tmax, 16));
        tmax = fmaxf(tmax, __shfl_xor(tmax, 32));

        // T13 defer-max: skip rescale when growth small (wave-uniform)
        if (!__all(tmax - m_q <= 8.f)) {
            const float nm = fmaxf(m_q, tmax);
            const float scl = __expf(m_q - nm);
            m_q = nm;
            l_q *= scl;
            #pragma unroll
            for (int r = 0; r < 4; ++r) {
                const float so = __shfl(scl, hi * 4 + r);
                #pragma unroll
                for (int n = 0; n < 4; ++n) oacc[n][r] *= so;
            }
        }

        // P = exp(S - m), packed bf16x4 writes; row-sum
        float ps = 0.f;
        #pragma unroll
        for (int ct = 0; ct < 4; ++ct) {
            bf16x4 pv4;
            #pragma unroll
            for (int r = 0; r < 4; ++r) {
                const float p = __expf(st[ct][r] - m_q);
                ps += p;
                pv4[r] = (bf16)p;
            }
            *(bf16x4*)&qp_lds[w * 16 + lo][ct * 16 + hi * 4] = pv4;
        }
        ps += __shfl_xor(ps, 16);
        ps += __shfl_xor(ps, 32);
        l_q += ps;

        asm volatile("s_waitcnt lgkmcnt(0)" ::: "memory");

        // O += P @ V
        #pragma unroll
        for (int n = 0; n < 4; ++n) {
            const int g = (((n * 16 + lo) >> 3) & 7) << 3;
            #pragma unroll
            for (int kk = 0; kk < 2; ++kk) {
                bf16x8 a  = *(const bf16x8*)&qp_lds[w * 16 + lo][kk * 32 + hi * 8];
                bf16x8 bv = *(const bf16x8*)&vt_lds[cur][n * 16 + lo][(kk * 32 + hi * 8) ^ g];
                oacc[n] = __builtin_amdgcn_mfma_f32_16x16x32_bf16(a, bv, oacc[n], 0, 0, 0);
            }
        }

        // write prefetched K/V into the other buffer
        if (kt < 15) {
            #pragma unroll
            for (int i = 0; i < 2; ++i) {
                const int e = (i * 256 + tid) * 8;
                const int r = e >> 6, c = e & 63;
                *(uint4*)&k_lds[nxt][r][c] = kreg[i];
                const bf16* pv = (const bf16*)&vreg[i];
                const int colS = r ^ (((c >> 3) & 7) << 3);
                #pragma unroll
                for (int j = 0; j < 8; ++j) vt_lds[nxt][c + j][colS] = pv[j];
            }
        }
        __syncthreads();
    }

    // epilogue: ctx[b, s, h, d] = O / l   (l broadcast from lane lo = row)
    #pragma unroll
    for (int r = 0; r < 4; ++r) {
        const float lr = __shfl(l_q, hi * 4 + r);
        const float inv = 1.f / lr;
        const size_t srow = (size_t)bb * SEQ + qt * 64 + w * 16 + hi * 4 + r;
        const size_t base = (srow * N_HEADS + hh) * D_HEAD;
        #pragma unroll
        for (int n = 0; n < 4; ++n)
            ctx[base + n * 16 + lo] = (bf16)(oacc[n][r] * inv);
    }
}

// =======================================================================
extern "C" void kernel_launch(void* const* d_in, const int* in_sizes, int n_in,
                              void* d_out, int out_size, void* d_ws, size_t ws_size,
                              hipStream_t stream)
{
    const float* x      = (const float*)d_in[0];
    const unsigned char* mask = (const unsigned char*)d_in[1];
    const float* gamma1 = (const float*)d_in[2];
    const float* beta1  = (const float*)d_in[3];
    const float* Wq     = (const float*)d_in[4];
    const float* bq     = (const float*)d_in[5];
    const float* Wk     = (const float*)d_in[6];
    const float* bk     = (const float*)d_in[7];
    const float* Wv     = (const float*)d_in[8];
    const float* bv     = (const float*)d_in[9];
    const float* Wo     = (const float*)d_in[10];
    const float* bo     = (const float*)d_in[11];
    const float* gamma2 = (const float*)d_in[12];
    const float* beta2  = (const float*)d_in[13];
    const float* W1     = (const float*)d_in[14];
    const float* b1     = (const float*)d_in[15];
    const float* W2     = (const float*)d_in[16];
    const float* b2     = (const float*)d_in[17];

    char* ws = (char*)d_ws;
    const size_t MB = 1u << 20;
    bf16* wqkv = (bf16*)(ws + 0 * MB);    // [3072][1024] bf16 (6MB)
    bf16* wot  = (bf16*)(ws + 6 * MB);    // [1024][1024] (2MB)
    bf16* w1t  = (bf16*)(ws + 8 * MB);    // [4096][1024] (8MB)
    bf16* w2t  = (bf16*)(ws + 16 * MB);   // [1024][4096] (8MB), written AFTER attn
    unsigned long long* mbits = (unsigned long long*)(ws + 16 * MB); // 1MB, dead before w2t
    float* bqkv = (float*)(ws + 17 * MB); // 12KB, dead before w2t
    bf16* xn1b = (bf16*)(ws + 24 * MB);   // [8192][1024] (16MB)
    float* xn1f = (float*)(ws + 40 * MB); // (32MB)
    bf16* qkv  = (bf16*)(ws + 72 * MB);   // [3][b,h,s,d] (48MB)
    bf16* ctx  = (bf16*)(ws + 120 * MB);  // [b,s,h,d] (16MB)
    bf16* hbuf = (bf16*)(ws + 72 * MB);   // [8192][4096] (64MB) aliases qkv+ctx (dead)
    bf16* xn2b = (bf16*)(ws + 136 * MB);  // (16MB)
    float* xn2f = (float*)(ws + 152 * MB);// (32MB) -> total 184MB
    float* x2f = (float*)d_out;           // reuse d_out as x2 scratch

    // weights -> bf16 transposed (W2 deferred: its slot holds mbits/bqkv now)
    wconv_t<<<dim3(32, 32),  256, 0, stream>>>(Wq, wqkv,               1024, 1024);
    wconv_t<<<dim3(32, 32),  256, 0, stream>>>(Wk, wqkv + 1024 * 1024, 1024, 1024);
    wconv_t<<<dim3(32, 32),  256, 0, stream>>>(Wv, wqkv + 2048 * 1024, 1024, 1024);
    wconv_t<<<dim3(32, 32),  256, 0, stream>>>(Wo, wot, 1024, 1024);
    wconv_t<<<dim3(128, 32), 256, 0, stream>>>(W1, w1t, 1024, 4096);
    bconcat<<<12, 256, 0, stream>>>(bq, bk, bv, bqkv);
    mask_pack<<<32768, 256, 0, stream>>>(mask, mbits);

    // xn1 = LN1(x)
    ln_kernel<<<MROWS, 256, 0, stream>>>(x, gamma1, beta1, xn1b, xn1f);

    // merged q,k,v projection: [8192,1024] @ [1024,3072]
    gemm_bt<0><<<24 * 64, 256, 0, stream>>>(xn1b, wqkv, bqkv, nullptr, qkv, MROWS, 3072, 1024, 24);

    // attention
    attn_kernel<<<2048, 256, 0, stream>>>(qkv, qkv + (size_t)MROWS * 1024,
                                          qkv + (size_t)2 * MROWS * 1024, mbits, ctx);

    // W2 convert now (slot shared with mbits/bqkv, both dead after attn/QKV)
    wconv_t<<<dim3(32, 128), 256, 0, stream>>>(W2, w2t, 4096, 1024);

    // x2 = xn1 + ctx @ Wo + bo   (into d_out as scratch)
    gemm_bt<1><<<8 * 64, 256, 0, stream>>>(ctx, wot, bo, xn1f, x2f, MROWS, 1024, 1024, 8);

    // xn2 = LN2(x2)
    ln_kernel<<<MROWS, 256, 0, stream>>>(x2f, gamma2, beta2, xn2b, xn2f);

    // h = relu(xn2 @ W1 + b1)
    gemm_bt<2><<<32 * 64, 256, 0, stream>>>(xn2b, w1t, b1, nullptr, hbuf, MROWS, 4096, 1024, 32);

    // out = xn2 + h @ W2 + b2
    gemm_bt<1><<<8 * 64, 256, 0, stream>>>(hbuf, w2t, b2, xn2f, (float*)d_out, MROWS, 1024, 4096, 8);
}